// Round 3
// baseline (857.134 us; speedup 1.0000x reference)
//
#include <hip/hip_runtime.h>
#include <hip/hip_bf16.h>
#include <stddef.h>

typedef __attribute__((ext_vector_type(8))) short short8;
typedef __attribute__((ext_vector_type(4))) float f32x4;

#define EPSB 1e-5f
#define BSZ 2048
#define NENT 50000
#define KFC 25600          // 64*400
#define NPOP 819200.0f     // 2048*400

__device__ __forceinline__ float bf2f(unsigned short h) {
    unsigned u = ((unsigned)h) << 16; float f; __builtin_memcpy(&f, &u, 4); return f;
}
__device__ __forceinline__ unsigned short f2bf(float f) {
    unsigned u; __builtin_memcpy(&u, &f, 4);
    unsigned r = u + 0x7fffu + ((u >> 16) & 1u);
    return (unsigned short)(r >> 16);
}

// ---------------- K1: gather + chequer perm + bn0 partials (no hot atomics) ----------------
__global__ void k_gather(const float* __restrict__ nf, const float* __restrict__ rf,
                         const int* __restrict__ sub, const int* __restrict__ rel,
                         float* __restrict__ x, float* __restrict__ gpart) {
    int idx = blockIdx.x * 256 + threadIdx.x;      // grid 3200*256 = 819200 exact
    int b = idx / 400, pos = idx % 400;
    int i = pos / 20, r = pos % 20;
    int src = i * 10 + (r >> 1) + (((i ^ r) & 1) * 200);
    float v = (src < 200) ? nf[(size_t)sub[b] * 200 + src]
                          : rf[(size_t)rel[b] * 200 + (src - 200)];
    x[idx] = v;
    float s1 = v, s2 = v * v;
    #pragma unroll
    for (int off = 32; off; off >>= 1) {
        s1 += __shfl_down(s1, off, 64);
        s2 += __shfl_down(s2, off, 64);
    }
    if ((threadIdx.x & 63) == 0) {
        int wid = blockIdx.x * 4 + (threadIdx.x >> 6);   // 12800 waves total
        gpart[wid * 2]     = s1;
        gpart[wid * 2 + 1] = s2;
    }
}

// ---------------- K1b: reduce 12800 wave partials -> stats[0..1] ----------------
__global__ void k_gfin(const float* __restrict__ gpart, float* __restrict__ stats) {
    int t = threadIdx.x;
    float s1 = 0.f, s2 = 0.f;
    for (int i = t; i < 12800; i += 256) {
        s1 += gpart[i * 2];
        s2 += gpart[i * 2 + 1];
    }
    #pragma unroll
    for (int off = 32; off; off >>= 1) {
        s1 += __shfl_down(s1, off, 64);
        s2 += __shfl_down(s2, off, 64);
    }
    __shared__ float red[8];
    if ((t & 63) == 0) { red[(t >> 6) * 2] = s1; red[(t >> 6) * 2 + 1] = s2; }
    __syncthreads();
    if (t == 0) {
        stats[0] = red[0] + red[2] + red[4] + red[6];
        stats[1] = red[1] + red[3] + red[5] + red[7];
    }
}

// ---------------- convert fc_w -> bf16 padded to 208 rows (vectorized: 8 elems/thread) ----------------
__global__ void k_fcw(const float* __restrict__ fcw, unsigned short* __restrict__ fcwb) {
    int idx = blockIdx.x * 256 + threadIdx.x;      // grid 2600*256 = 665600 = 208*3200 exact
    int d = idx / 3200, g = idx % 3200;
    int k = g * 8;
    short8 o = {};
    unsigned short* op = (unsigned short*)&o;
    if (d < 200) {
        float4 a = *(const float4*)(fcw + (size_t)d * KFC + k);
        float4 b = *(const float4*)(fcw + (size_t)d * KFC + k + 4);
        op[0] = f2bf(a.x); op[1] = f2bf(a.y); op[2] = f2bf(a.z); op[3] = f2bf(a.w);
        op[4] = f2bf(b.x); op[5] = f2bf(b.y); op[6] = f2bf(b.z); op[7] = f2bf(b.w);
    }
    *(short8*)(fcwb + (size_t)idx * 8) = o;
}

// ---------------- convert n_feats -> bf16 padded (50048 x 224, vectorized) ----------------
__global__ void k_nfb(const float* __restrict__ nf, unsigned short* __restrict__ nfb) {
    int idx = blockIdx.x * 256 + threadIdx.x;      // grid 5474*256 = 1401344 = 50048*28 exact
    int e = idx / 28, g = idx % 28;
    int k = g * 8;
    short8 o = {};
    unsigned short* op = (unsigned short*)&o;
    if (e < NENT && k < 200) {
        float4 a = *(const float4*)(nf + (size_t)e * 200 + k);
        float4 b = *(const float4*)(nf + (size_t)e * 200 + k + 4);
        op[0] = f2bf(a.x); op[1] = f2bf(a.y); op[2] = f2bf(a.z); op[3] = f2bf(a.w);
        op[4] = f2bf(b.x); op[5] = f2bf(b.y); op[6] = f2bf(b.z); op[7] = f2bf(b.w);
    }
    *(short8*)(nfb + (size_t)idx * 8) = o;
}

// ---------------- K2: bn0 + per-sample dynamic conv + channel partials ----------------
__global__ void k_conv(const float* __restrict__ x, const float* __restrict__ fw,
                       const int* __restrict__ rel,
                       const float* __restrict__ bn0g, const float* __restrict__ bn0b,
                       const float* __restrict__ stats,
                       unsigned short* __restrict__ z,
                       float* __restrict__ chpart) {
    __shared__ float xt[22 * 22];
    __shared__ float ft[576];
    __shared__ unsigned short zb[64 * 402];   // stride 402 to break bank stride
    __shared__ float red[512];
    int b = blockIdx.x, t = threadIdx.x;

    float m0 = stats[0] * (1.f / NPOP);
    float v0 = fmaxf(stats[1] * (1.f / NPOP) - m0 * m0, 0.f);
    float inv0 = rsqrtf(v0 + EPSB);
    float a0 = bn0g[0] * inv0;
    float c0 = bn0b[0] - a0 * m0;

    for (int q = t; q < 484; q += 256) {
        int i = q / 22, j = q % 22;
        float val = 0.f;
        if (i >= 1 && i <= 20 && j >= 1 && j <= 20)
            val = a0 * x[b * 400 + (i - 1) * 20 + (j - 1)] + c0;
        xt[q] = val;
    }
    int rb = rel[b];
    for (int q = t; q < 576; q += 256) ft[q] = fw[(size_t)rb * 576 + q];
    __syncthreads();

    int oc = t >> 2, qq = t & 3;
    float f0 = ft[oc * 9 + 0], f1 = ft[oc * 9 + 1], f2 = ft[oc * 9 + 2];
    float f3 = ft[oc * 9 + 3], f4 = ft[oc * 9 + 4], f5 = ft[oc * 9 + 5];
    float f6 = ft[oc * 9 + 6], f7 = ft[oc * 9 + 7], f8 = ft[oc * 9 + 8];
    float cs1 = 0.f, cs2 = 0.f;
    // strength-reduced: no div/mod in hot loop; paired bf16 stores (b32)
    #pragma unroll
    for (int ri = 0; ri < 5; ++ri) {
        int i = qq * 5 + ri;
        const float* xr = &xt[i * 22];
        #pragma unroll
        for (int j = 0; j < 20; j += 2) {
            float a0v = f0 * xr[j]      + f1 * xr[j + 1]  + f2 * xr[j + 2]
                      + f3 * xr[j + 22] + f4 * xr[j + 23] + f5 * xr[j + 24]
                      + f6 * xr[j + 44] + f7 * xr[j + 45] + f8 * xr[j + 46];
            float a1v = f0 * xr[j + 1]  + f1 * xr[j + 2]  + f2 * xr[j + 3]
                      + f3 * xr[j + 23] + f4 * xr[j + 24] + f5 * xr[j + 25]
                      + f6 * xr[j + 45] + f7 * xr[j + 46] + f8 * xr[j + 47];
            unsigned pk = (unsigned)f2bf(a0v) | ((unsigned)f2bf(a1v) << 16);
            *(unsigned*)(&zb[oc * 402 + i * 20 + j]) = pk;
            cs1 += a0v + a1v; cs2 += a0v * a0v + a1v * a1v;
        }
    }
    red[t] = cs1; red[256 + t] = cs2;
    __syncthreads();
    if (t < 64) {
        float a  = red[t * 4] + red[t * 4 + 1] + red[t * 4 + 2] + red[t * 4 + 3];
        float sq = red[256 + t * 4] + red[256 + t * 4 + 1] + red[256 + t * 4 + 2] + red[256 + t * 4 + 3];
        chpart[(size_t)b * 128 + t]      = a;
        chpart[(size_t)b * 128 + 64 + t] = sq;
    }
    // coalesced store of z (pairs)
    unsigned int* zout = (unsigned int*)(z + (size_t)b * KFC);
    #pragma unroll 2
    for (int kk = 0; kk < 50; ++kk) {
        int pidx = kk * 256 + t;
        int idx2 = pidx * 2;
        int o2 = idx2 / 400, p2 = idx2 % 400;
        zout[pidx] = *(const unsigned int*)&zb[o2 * 402 + p2];
    }
}

// ---------------- K3: reduce channel partials + composed double-BN affine ----------------
__global__ void k_chfin(const float* __restrict__ chpart,
                        const float* __restrict__ cg, const float* __restrict__ cb,
                        const float* __restrict__ g1, const float* __restrict__ b1,
                        float* __restrict__ scaleA, float* __restrict__ biasA) {
    int oc = blockIdx.x, t = threadIdx.x;
    float a = 0.f, sq = 0.f;
    for (int b = t; b < BSZ; b += 256) {
        a  += chpart[(size_t)b * 128 + oc];
        sq += chpart[(size_t)b * 128 + 64 + oc];
    }
    #pragma unroll
    for (int off = 32; off; off >>= 1) {
        a  += __shfl_down(a, off, 64);
        sq += __shfl_down(sq, off, 64);
    }
    __shared__ float red[8];
    if ((t & 63) == 0) { red[(t >> 6) * 2] = a; red[(t >> 6) * 2 + 1] = sq; }
    __syncthreads();
    if (t == 0) {
        float m = (red[0] + red[2] + red[4] + red[6]) * (1.f / NPOP);
        float v = fmaxf((red[1] + red[3] + red[5] + red[7]) * (1.f / NPOP) - m * m, 0.f);
        float d1 = v + EPSB;
        float varY = cg[oc] * cg[oc] * v / d1;       // exact var after first BN
        float A = g1[oc] * cg[oc] * rsqrtf(d1) * rsqrtf(varY + EPSB);
        scaleA[oc] = A;
        biasA[oc]  = b1[oc] - A * m;                 // mean after first BN == cb, cancels
    }
}

__device__ __forceinline__ short8 cvt_affine(uint4 raw, float Ac, float Bc) {
    short8 af;
    const unsigned short* ap = (const unsigned short*)&raw;
    unsigned short* fp = (unsigned short*)&af;
    #pragma unroll
    for (int j = 0; j < 8; ++j) {
        float y = fmaxf(Ac * bf2f(ap[j]) + Bc, 0.f);
        fp[j] = f2bf(y);
    }
    return af;
}

// ---------------- K4: FC GEMM, BK=64, dbuf LDS + async-stage split, 1 barrier/step ----------------
__launch_bounds__(256)
__global__ void k_fc(const unsigned short* __restrict__ z, const unsigned short* __restrict__ fcwb,
                     const float* __restrict__ scaleA, const float* __restrict__ biasA,
                     float* __restrict__ hp) {
    __shared__ unsigned short Bt[2][208 * 72];   // 2 x 29,952 B (row stride 72 -> 2-way bank, free)
    int bx = blockIdx.x;                         // grid 512 = 32 mblk * 16 ksplit
    int mblk = bx & 31, s = bx >> 5;
    int t = threadIdx.x, wave = t >> 6, lane = t & 63;
    int l15 = lane & 15, l4 = lane >> 4;

    f32x4 acc[13] = {};
    int row = mblk * 64 + wave * 16 + l15;
    const unsigned short* zrow = z + (size_t)row * KFC + s * 1600;
    const unsigned short* fbase = fcwb + s * 1600;

    // staging map: 1664 uint4 per 64-wide K tile; idx -> d = idx>>3, g = idx&7
    uint4 pre[7];
    #pragma unroll
    for (int j = 0; j < 7; ++j) {
        int idx = t + j * 256;
        if (idx < 1664) {
            int d = idx >> 3, g = idx & 7;
            pre[j] = *(const uint4*)(fbase + (size_t)d * KFC + g * 8);      // st=0
        }
    }
    uint4 zA = *(const uint4*)(zrow + l4 * 8);
    uint4 zB = *(const uint4*)(zrow + 32 + l4 * 8);
    #pragma unroll
    for (int j = 0; j < 7; ++j) {
        int idx = t + j * 256;
        if (idx < 1664) { int d = idx >> 3, g = idx & 7; *(uint4*)(&Bt[0][d * 72 + g * 8]) = pre[j]; }
    }
    __syncthreads();

    for (int st = 0; st < 25; ++st) {
        int cur = st & 1;
        uint4 zA2, zB2;
        if (st + 1 < 25) {
            // T14: issue next-tile global loads now; consume after compute
            #pragma unroll
            for (int j = 0; j < 7; ++j) {
                int idx = t + j * 256;
                if (idx < 1664) {
                    int d = idx >> 3, g = idx & 7;
                    pre[j] = *(const uint4*)(fbase + (size_t)d * KFC + (st + 1) * 64 + g * 8);
                }
            }
            zA2 = *(const uint4*)(zrow + (st + 1) * 64 + l4 * 8);
            zB2 = *(const uint4*)(zrow + (st + 1) * 64 + 32 + l4 * 8);
        }
        // compute current tile
        int k0 = st * 64 + l4 * 8;              // within this ksplit (mult of 8; channel-safe)
        int kg0 = s * 1600 + k0;
        int c0 = (unsigned)kg0 / 400u;
        int c1 = (unsigned)(kg0 + 32) / 400u;
        short8 af0 = cvt_affine(zA, scaleA[c0], biasA[c0]);
        short8 af1 = cvt_affine(zB, scaleA[c1], biasA[c1]);
        #pragma unroll
        for (int nt = 0; nt < 13; ++nt) {
            short8 bf0 = *(const short8*)(&Bt[cur][(nt * 16 + l15) * 72 + l4 * 8]);
            acc[nt] = __builtin_amdgcn_mfma_f32_16x16x32_bf16(af0, bf0, acc[nt], 0, 0, 0);
            short8 bf1 = *(const short8*)(&Bt[cur][(nt * 16 + l15) * 72 + 32 + l4 * 8]);
            acc[nt] = __builtin_amdgcn_mfma_f32_16x16x32_bf16(af1, bf1, acc[nt], 0, 0, 0);
        }
        if (st + 1 < 25) {
            #pragma unroll
            for (int j = 0; j < 7; ++j) {
                int idx = t + j * 256;
                if (idx < 1664) { int d = idx >> 3, g = idx & 7; *(uint4*)(&Bt[cur ^ 1][d * 72 + g * 8]) = pre[j]; }
            }
            zA = zA2; zB = zB2;
        }
        __syncthreads();     // orders write(next buf) before next step's reads; 1 barrier/step
    }
    float* hrow = hp + ((size_t)s * BSZ + (size_t)mblk * 64 + wave * 16) * 208;
    #pragma unroll
    for (int nt = 0; nt < 13; ++nt)
        #pragma unroll
        for (int r = 0; r < 4; ++r)
            hrow[(l4 * 4 + r) * 208 + nt * 16 + l15] = acc[nt][r];
}

// ---------------- K5: reduce k-split partials + bn1d column stats (128 blocks) ----------------
__global__ void k_hred(const float* __restrict__ hp, float* __restrict__ h,
                       float* __restrict__ colsum, float* __restrict__ colsumsq) {
    int blk = blockIdx.x;   // 128 blocks * 16 rows
    int t = threadIdx.x;
    if (t >= 208) return;
    float cs = 0.f, css = 0.f;
    for (int r = 0; r < 16; ++r) {
        int row = blk * 16 + r;
        float v = 0.f;
        #pragma unroll
        for (int s2 = 0; s2 < 16; ++s2)
            v += hp[((size_t)s2 * BSZ + row) * 208 + t];
        h[(size_t)row * 208 + t] = v;
        cs += v; css += v * v;
    }
    atomicAdd(&colsum[t], cs); atomicAdd(&colsumsq[t], css);   // 128-deep per address
}

// ---------------- K5c: apply bn1d + relu -> h2 bf16 (2048 x 224, zero pad) ----------------
__global__ void k_bnapply(const float* __restrict__ h,
                          const float* __restrict__ colsum, const float* __restrict__ colsumsq,
                          const float* __restrict__ g2, const float* __restrict__ b2,
                          unsigned short* __restrict__ h2) {
    int idx = blockIdx.x * 256 + threadIdx.x;   // grid 1792*256 = 2048*224 exact
    int b = idx / 224, d = idx % 224;
    float out = 0.f;
    if (d < 200) {
        float m = colsum[d] * (1.f / 2048.f);
        float v = fmaxf(colsumsq[d] * (1.f / 2048.f) - m * m, 0.f);
        float val = g2[d] * (h[(size_t)b * 208 + d] - m) * rsqrtf(v + EPSB) + b2[d];
        out = fmaxf(val, 0.f);
    }
    h2[idx] = f2bf(out);
}

// ---------------- K6: out = h2 @ n_feats^T + ent_bias (128 rows/block) ----------------
__launch_bounds__(256)
__global__ void k_out(const unsigned short* __restrict__ h2, const unsigned short* __restrict__ nfb,
                      const float* __restrict__ entb, float* __restrict__ out) {
    __shared__ unsigned short At[128 * 232];    // 128 rows x 224 (stride 232 -> 2-way bank, free)
    int bx = blockIdx.x;                        // grid 12512 = 16 mblk (fast) * 782 nblk
    int mblk = bx & 15, nblk = bx >> 4;
    int t = threadIdx.x, wave = t >> 6, lane = t & 63;
    int l15 = lane & 15, l4 = lane >> 4;

    const unsigned short* hbase = h2 + (size_t)mblk * 128 * 224;
    for (int f = t; f < 3584; f += 256) {       // 128 rows * 28 x 16B
        int row = f / 28, g = f % 28;
        *(uint4*)(&At[row * 232 + g * 8]) = *(const uint4*)(hbase + (size_t)row * 224 + g * 8);
    }
    __syncthreads();

    f32x4 acc[8] = {};
    int e = nblk * 64 + wave * 16 + l15;
    const unsigned short* brow = nfb + (size_t)e * 224;
    short8 bfr[7];
    #pragma unroll
    for (int ks = 0; ks < 7; ++ks)
        bfr[ks] = *(const short8*)(brow + ks * 32 + l4 * 8);
    #pragma unroll
    for (int ks = 0; ks < 7; ++ks) {
        #pragma unroll
        for (int mt = 0; mt < 8; ++mt) {
            short8 af = *(const short8*)(&At[(mt * 16 + l15) * 232 + ks * 32 + l4 * 8]);
            acc[mt] = __builtin_amdgcn_mfma_f32_16x16x32_bf16(af, bfr[ks], acc[mt], 0, 0, 0);
        }
    }
    if (e < NENT) {
        float eb = entb[e];
        #pragma unroll
        for (int mt = 0; mt < 8; ++mt) {
            #pragma unroll
            for (int r = 0; r < 4; ++r) {
                int row = mblk * 128 + mt * 16 + l4 * 4 + r;
                out[(size_t)row * NENT + e] = acc[mt][r] + eb;
            }
        }
    }
}

extern "C" void kernel_launch(void* const* d_in, const int* in_sizes, int n_in,
                              void* d_out, int out_size, void* d_ws, size_t ws_size,
                              hipStream_t stream) {
    const float* n_feats  = (const float*)d_in[0];
    const float* r_feats  = (const float*)d_in[1];
    const float* filter_w = (const float*)d_in[2];
    const float* bn0_g = (const float*)d_in[3];
    const float* bn0_b = (const float*)d_in[4];
    const float* cbn_g = (const float*)d_in[5];
    const float* cbn_b = (const float*)d_in[6];
    const float* bn1_g = (const float*)d_in[7];
    const float* bn1_b = (const float*)d_in[8];
    const float* fc_w  = (const float*)d_in[9];
    // d_in[10] = fc_b : cancels exactly through training-mode bn1d (shift-invariant)
    const float* bn2_g = (const float*)d_in[11];
    const float* bn2_b = (const float*)d_in[12];
    const float* ent_bias = (const float*)d_in[13];
    const int* sub = (const int*)d_in[14];
    const int* rel = (const int*)d_in[15];
    float* out = (float*)d_out;

    char* ws = (char*)d_ws;
    // workspace layout (all 512B-aligned)
    float*          stats = (float*)(ws + 0);                 // 8192 B region
    float*          colsum  = stats + 130;
    float*          colsumsq= stats + 338;
    float*          scaleA  = stats + 1024;
    float*          biasA   = stats + 1088;
    float*          x    = (float*)(ws + 8192);                            // 3,276,800
    unsigned short* z    = (unsigned short*)(ws + 3284992);                // 104,857,600
    unsigned short* fcwb = (unsigned short*)(ws + 108142592);              // 10,649,600
    float*          hp   = (float*)(ws + 118792192);                       // 27,262,976
    float*          h    = (float*)(ws + 146055168);                       // 1,703,936
    unsigned short* h2   = (unsigned short*)(ws + 147759104);              // 917,504
    unsigned short* nfb  = (unsigned short*)(ws + 148676608);              // 22,421,504

    // scratch partials live inside hp's region: hp is fully overwritten by k_fc,
    // which runs only after k_gfin/k_chfin have consumed these (stream-ordered).
    float*          gpart  = (float*)(ws + 118792192);                     // 12800*2*4 = 102,400
    float*          chpart = (float*)(ws + 118792192 + 131072);            // 2048*128*4 = 1,048,576

    hipMemsetAsync(stats, 0, 8192, stream);    // colsum/colsumsq zeroing (k_hred atomics)

    k_gather<<<3200, 256, 0, stream>>>(n_feats, r_feats, sub, rel, x, gpart);
    k_gfin<<<1, 256, 0, stream>>>(gpart, stats);
    k_fcw<<<2600, 256, 0, stream>>>(fc_w, fcwb);
    k_nfb<<<5474, 256, 0, stream>>>(n_feats, nfb);
    k_conv<<<2048, 256, 0, stream>>>(x, filter_w, rel, bn0_g, bn0_b, stats, z, chpart);
    k_chfin<<<64, 256, 0, stream>>>(chpart, cbn_g, cbn_b, bn1_g, bn1_b, scaleA, biasA);
    k_fc<<<512, 256, 0, stream>>>(z, fcwb, scaleA, biasA, hp);
    k_hred<<<128, 256, 0, stream>>>(hp, h, colsum, colsumsq);
    k_bnapply<<<1792, 256, 0, stream>>>(h, colsum, colsumsq, bn2_g, bn2_b, h2);
    k_out<<<12512, 256, 0, stream>>>(h2, nfb, ent_bias, out);
}

// Round 4
// 811.926 us; speedup vs baseline: 1.0557x; 1.0557x over previous
//
#include <hip/hip_runtime.h>
#include <hip/hip_bf16.h>
#include <stddef.h>

typedef __attribute__((ext_vector_type(8))) short short8;
typedef __attribute__((ext_vector_type(4))) float f32x4;

#define EPSB 1e-5f
#define BSZ 2048
#define NENT 50000
#define KFC 25600          // 64*400
#define NPOP 819200.0f     // 2048*400

__device__ __forceinline__ float bf2f(unsigned short h) {
    unsigned u = ((unsigned)h) << 16; float f; __builtin_memcpy(&f, &u, 4); return f;
}
__device__ __forceinline__ unsigned short f2bf(float f) {
    unsigned u; __builtin_memcpy(&u, &f, 4);
    unsigned r = u + 0x7fffu + ((u >> 16) & 1u);
    return (unsigned short)(r >> 16);
}

// ---------------- K1: gather + chequer perm + bn0 partials (no hot atomics) ----------------
__global__ void k_gather(const float* __restrict__ nf, const float* __restrict__ rf,
                         const int* __restrict__ sub, const int* __restrict__ rel,
                         float* __restrict__ x, float* __restrict__ gpart) {
    int idx = blockIdx.x * 256 + threadIdx.x;      // grid 3200*256 = 819200 exact
    int b = idx / 400, pos = idx % 400;
    int i = pos / 20, r = pos % 20;
    int src = i * 10 + (r >> 1) + (((i ^ r) & 1) * 200);
    float v = (src < 200) ? nf[(size_t)sub[b] * 200 + src]
                          : rf[(size_t)rel[b] * 200 + (src - 200)];
    x[idx] = v;
    float s1 = v, s2 = v * v;
    #pragma unroll
    for (int off = 32; off; off >>= 1) {
        s1 += __shfl_down(s1, off, 64);
        s2 += __shfl_down(s2, off, 64);
    }
    if ((threadIdx.x & 63) == 0) {
        int wid = blockIdx.x * 4 + (threadIdx.x >> 6);   // 12800 waves total
        gpart[wid * 2]     = s1;
        gpart[wid * 2 + 1] = s2;
    }
}

// ---------------- K1b: reduce 12800 wave partials -> stats[0..1] ----------------
__global__ void k_gfin(const float* __restrict__ gpart, float* __restrict__ stats) {
    int t = threadIdx.x;
    float s1 = 0.f, s2 = 0.f;
    for (int i = t; i < 12800; i += 256) {
        s1 += gpart[i * 2];
        s2 += gpart[i * 2 + 1];
    }
    #pragma unroll
    for (int off = 32; off; off >>= 1) {
        s1 += __shfl_down(s1, off, 64);
        s2 += __shfl_down(s2, off, 64);
    }
    __shared__ float red[8];
    if ((t & 63) == 0) { red[(t >> 6) * 2] = s1; red[(t >> 6) * 2 + 1] = s2; }
    __syncthreads();
    if (t == 0) {
        stats[0] = red[0] + red[2] + red[4] + red[6];
        stats[1] = red[1] + red[3] + red[5] + red[7];
    }
}

// ---------------- convert fc_w -> bf16 padded to 208 rows (vectorized: 8 elems/thread) ----------------
__global__ void k_fcw(const float* __restrict__ fcw, unsigned short* __restrict__ fcwb) {
    int idx = blockIdx.x * 256 + threadIdx.x;      // grid 2600*256 = 665600 = 208*3200 exact
    int d = idx / 3200, g = idx % 3200;
    int k = g * 8;
    short8 o = {};
    unsigned short* op = (unsigned short*)&o;
    if (d < 200) {
        float4 a = *(const float4*)(fcw + (size_t)d * KFC + k);
        float4 b = *(const float4*)(fcw + (size_t)d * KFC + k + 4);
        op[0] = f2bf(a.x); op[1] = f2bf(a.y); op[2] = f2bf(a.z); op[3] = f2bf(a.w);
        op[4] = f2bf(b.x); op[5] = f2bf(b.y); op[6] = f2bf(b.z); op[7] = f2bf(b.w);
    }
    *(short8*)(fcwb + (size_t)idx * 8) = o;
}

// ---------------- convert n_feats -> bf16 padded (50048 x 224, vectorized) ----------------
__global__ void k_nfb(const float* __restrict__ nf, unsigned short* __restrict__ nfb) {
    int idx = blockIdx.x * 256 + threadIdx.x;      // grid 5474*256 = 1401344 = 50048*28 exact
    int e = idx / 28, g = idx % 28;
    int k = g * 8;
    short8 o = {};
    unsigned short* op = (unsigned short*)&o;
    if (e < NENT && k < 200) {
        float4 a = *(const float4*)(nf + (size_t)e * 200 + k);
        float4 b = *(const float4*)(nf + (size_t)e * 200 + k + 4);
        op[0] = f2bf(a.x); op[1] = f2bf(a.y); op[2] = f2bf(a.z); op[3] = f2bf(a.w);
        op[4] = f2bf(b.x); op[5] = f2bf(b.y); op[6] = f2bf(b.z); op[7] = f2bf(b.w);
    }
    *(short8*)(nfb + (size_t)idx * 8) = o;
}

// ---------------- K2: bn0 + per-sample dynamic conv + channel partials ----------------
__global__ void k_conv(const float* __restrict__ x, const float* __restrict__ fw,
                       const int* __restrict__ rel,
                       const float* __restrict__ bn0g, const float* __restrict__ bn0b,
                       const float* __restrict__ stats,
                       unsigned short* __restrict__ z,
                       float* __restrict__ chpart) {
    __shared__ float xt[22 * 22];
    __shared__ float ft[576];
    __shared__ unsigned short zb[64 * 402];   // stride 402 to break bank stride
    __shared__ float red[512];
    int b = blockIdx.x, t = threadIdx.x;

    float m0 = stats[0] * (1.f / NPOP);
    float v0 = fmaxf(stats[1] * (1.f / NPOP) - m0 * m0, 0.f);
    float inv0 = rsqrtf(v0 + EPSB);
    float a0 = bn0g[0] * inv0;
    float c0 = bn0b[0] - a0 * m0;

    for (int q = t; q < 484; q += 256) {
        int i = q / 22, j = q % 22;
        float val = 0.f;
        if (i >= 1 && i <= 20 && j >= 1 && j <= 20)
            val = a0 * x[b * 400 + (i - 1) * 20 + (j - 1)] + c0;
        xt[q] = val;
    }
    int rb = rel[b];
    for (int q = t; q < 576; q += 256) ft[q] = fw[(size_t)rb * 576 + q];
    __syncthreads();

    int oc = t >> 2, qq = t & 3;
    float f0 = ft[oc * 9 + 0], f1 = ft[oc * 9 + 1], f2 = ft[oc * 9 + 2];
    float f3 = ft[oc * 9 + 3], f4 = ft[oc * 9 + 4], f5 = ft[oc * 9 + 5];
    float f6 = ft[oc * 9 + 6], f7 = ft[oc * 9 + 7], f8 = ft[oc * 9 + 8];
    float cs1 = 0.f, cs2 = 0.f;
    // strength-reduced: no div/mod in hot loop; paired bf16 stores (b32)
    #pragma unroll
    for (int ri = 0; ri < 5; ++ri) {
        int i = qq * 5 + ri;
        const float* xr = &xt[i * 22];
        #pragma unroll
        for (int j = 0; j < 20; j += 2) {
            float a0v = f0 * xr[j]      + f1 * xr[j + 1]  + f2 * xr[j + 2]
                      + f3 * xr[j + 22] + f4 * xr[j + 23] + f5 * xr[j + 24]
                      + f6 * xr[j + 44] + f7 * xr[j + 45] + f8 * xr[j + 46];
            float a1v = f0 * xr[j + 1]  + f1 * xr[j + 2]  + f2 * xr[j + 3]
                      + f3 * xr[j + 23] + f4 * xr[j + 24] + f5 * xr[j + 25]
                      + f6 * xr[j + 45] + f7 * xr[j + 46] + f8 * xr[j + 47];
            unsigned pk = (unsigned)f2bf(a0v) | ((unsigned)f2bf(a1v) << 16);
            *(unsigned*)(&zb[oc * 402 + i * 20 + j]) = pk;
            cs1 += a0v + a1v; cs2 += a0v * a0v + a1v * a1v;
        }
    }
    red[t] = cs1; red[256 + t] = cs2;
    __syncthreads();
    if (t < 64) {
        float a  = red[t * 4] + red[t * 4 + 1] + red[t * 4 + 2] + red[t * 4 + 3];
        float sq = red[256 + t * 4] + red[256 + t * 4 + 1] + red[256 + t * 4 + 2] + red[256 + t * 4 + 3];
        chpart[(size_t)b * 128 + t]      = a;
        chpart[(size_t)b * 128 + 64 + t] = sq;
    }
    // coalesced store of z (pairs)
    unsigned int* zout = (unsigned int*)(z + (size_t)b * KFC);
    #pragma unroll 2
    for (int kk = 0; kk < 50; ++kk) {
        int pidx = kk * 256 + t;
        int idx2 = pidx * 2;
        int o2 = idx2 / 400, p2 = idx2 % 400;
        zout[pidx] = *(const unsigned int*)&zb[o2 * 402 + p2];
    }
}

// ---------------- K3: reduce channel partials + composed double-BN affine ----------------
__global__ void k_chfin(const float* __restrict__ chpart,
                        const float* __restrict__ cg, const float* __restrict__ cb,
                        const float* __restrict__ g1, const float* __restrict__ b1,
                        float* __restrict__ scaleA, float* __restrict__ biasA) {
    int oc = blockIdx.x, t = threadIdx.x;
    float a = 0.f, sq = 0.f;
    for (int b = t; b < BSZ; b += 256) {
        a  += chpart[(size_t)b * 128 + oc];
        sq += chpart[(size_t)b * 128 + 64 + oc];
    }
    #pragma unroll
    for (int off = 32; off; off >>= 1) {
        a  += __shfl_down(a, off, 64);
        sq += __shfl_down(sq, off, 64);
    }
    __shared__ float red[8];
    if ((t & 63) == 0) { red[(t >> 6) * 2] = a; red[(t >> 6) * 2 + 1] = sq; }
    __syncthreads();
    if (t == 0) {
        float m = (red[0] + red[2] + red[4] + red[6]) * (1.f / NPOP);
        float v = fmaxf((red[1] + red[3] + red[5] + red[7]) * (1.f / NPOP) - m * m, 0.f);
        float d1 = v + EPSB;
        float varY = cg[oc] * cg[oc] * v / d1;       // exact var after first BN
        float A = g1[oc] * cg[oc] * rsqrtf(d1) * rsqrtf(varY + EPSB);
        scaleA[oc] = A;
        biasA[oc]  = b1[oc] - A * m;                 // mean after first BN == cb, cancels
    }
}

__device__ __forceinline__ short8 cvt_affine(uint4 raw, float Ac, float Bc) {
    short8 af;
    const unsigned short* ap = (const unsigned short*)&raw;
    unsigned short* fp = (unsigned short*)&af;
    #pragma unroll
    for (int j = 0; j < 8; ++j) {
        float y = fmaxf(Ac * bf2f(ap[j]) + Bc, 0.f);
        fp[j] = f2bf(y);
    }
    return af;
}

// ---------------- K4: FC GEMM, BK=64, dbuf LDS + async-stage split, 1 barrier/step ----------------
__launch_bounds__(256)
__global__ void k_fc(const unsigned short* __restrict__ z, const unsigned short* __restrict__ fcwb,
                     const float* __restrict__ scaleA, const float* __restrict__ biasA,
                     float* __restrict__ hp) {
    __shared__ unsigned short Bt[2][208 * 72];   // 2 x 29,952 B (row stride 72 -> 2-way bank, free)
    int bx = blockIdx.x;                         // grid 512 = 32 mblk * 16 ksplit
    int mblk = bx & 31, s = bx >> 5;
    int t = threadIdx.x, wave = t >> 6, lane = t & 63;
    int l15 = lane & 15, l4 = lane >> 4;

    f32x4 acc[13] = {};
    int row = mblk * 64 + wave * 16 + l15;
    const unsigned short* zrow = z + (size_t)row * KFC + s * 1600;
    const unsigned short* fbase = fcwb + s * 1600;

    // staging map: 1664 uint4 per 64-wide K tile; idx -> d = idx>>3, g = idx&7
    uint4 pre[7];
    #pragma unroll
    for (int j = 0; j < 7; ++j) {
        int idx = t + j * 256;
        if (idx < 1664) {
            int d = idx >> 3, g = idx & 7;
            pre[j] = *(const uint4*)(fbase + (size_t)d * KFC + g * 8);      // st=0
        }
    }
    uint4 zA = *(const uint4*)(zrow + l4 * 8);
    uint4 zB = *(const uint4*)(zrow + 32 + l4 * 8);
    #pragma unroll
    for (int j = 0; j < 7; ++j) {
        int idx = t + j * 256;
        if (idx < 1664) { int d = idx >> 3, g = idx & 7; *(uint4*)(&Bt[0][d * 72 + g * 8]) = pre[j]; }
    }
    __syncthreads();

    for (int st = 0; st < 25; ++st) {
        int cur = st & 1;
        uint4 zA2, zB2;
        if (st + 1 < 25) {
            // T14: issue next-tile global loads now; consume after compute
            #pragma unroll
            for (int j = 0; j < 7; ++j) {
                int idx = t + j * 256;
                if (idx < 1664) {
                    int d = idx >> 3, g = idx & 7;
                    pre[j] = *(const uint4*)(fbase + (size_t)d * KFC + (st + 1) * 64 + g * 8);
                }
            }
            zA2 = *(const uint4*)(zrow + (st + 1) * 64 + l4 * 8);
            zB2 = *(const uint4*)(zrow + (st + 1) * 64 + 32 + l4 * 8);
        }
        // compute current tile
        int k0 = st * 64 + l4 * 8;              // within this ksplit (mult of 8; channel-safe)
        int kg0 = s * 1600 + k0;
        int c0 = (unsigned)kg0 / 400u;
        int c1 = (unsigned)(kg0 + 32) / 400u;
        short8 af0 = cvt_affine(zA, scaleA[c0], biasA[c0]);
        short8 af1 = cvt_affine(zB, scaleA[c1], biasA[c1]);
        #pragma unroll
        for (int nt = 0; nt < 13; ++nt) {
            short8 bf0 = *(const short8*)(&Bt[cur][(nt * 16 + l15) * 72 + l4 * 8]);
            acc[nt] = __builtin_amdgcn_mfma_f32_16x16x32_bf16(af0, bf0, acc[nt], 0, 0, 0);
            short8 bf1 = *(const short8*)(&Bt[cur][(nt * 16 + l15) * 72 + 32 + l4 * 8]);
            acc[nt] = __builtin_amdgcn_mfma_f32_16x16x32_bf16(af1, bf1, acc[nt], 0, 0, 0);
        }
        if (st + 1 < 25) {
            #pragma unroll
            for (int j = 0; j < 7; ++j) {
                int idx = t + j * 256;
                if (idx < 1664) { int d = idx >> 3, g = idx & 7; *(uint4*)(&Bt[cur ^ 1][d * 72 + g * 8]) = pre[j]; }
            }
            zA = zA2; zB = zB2;
        }
        __syncthreads();     // orders write(next buf) before next step's reads; 1 barrier/step
    }
    float* hrow = hp + ((size_t)s * BSZ + (size_t)mblk * 64 + wave * 16) * 208;
    #pragma unroll
    for (int nt = 0; nt < 13; ++nt)
        #pragma unroll
        for (int r = 0; r < 4; ++r)
            hrow[(l4 * 4 + r) * 208 + nt * 16 + l15] = acc[nt][r];
}

// ---------------- K5: reduce k-split partials + bn1d column stats (256 blocks x 8 rows) ----------------
__global__ void k_hred(const float* __restrict__ hp, float* __restrict__ h,
                       float* __restrict__ colsum, float* __restrict__ colsumsq) {
    int blk = blockIdx.x;   // 256 blocks * 8 rows
    int t = threadIdx.x;
    if (t >= 208) return;
    float cs = 0.f, css = 0.f;
    for (int r = 0; r < 8; ++r) {
        int row = blk * 8 + r;
        float v = 0.f;
        #pragma unroll
        for (int s2 = 0; s2 < 16; ++s2)
            v += hp[((size_t)s2 * BSZ + row) * 208 + t];
        h[(size_t)row * 208 + t] = v;
        cs += v; css += v * v;
    }
    atomicAdd(&colsum[t], cs); atomicAdd(&colsumsq[t], css);   // 256-deep per address, spread in time
}

// ---------------- K5c: apply bn1d + relu -> h2 bf16 (2048 x 224, zero pad) ----------------
__global__ void k_bnapply(const float* __restrict__ h,
                          const float* __restrict__ colsum, const float* __restrict__ colsumsq,
                          const float* __restrict__ g2, const float* __restrict__ b2,
                          unsigned short* __restrict__ h2) {
    int idx = blockIdx.x * 256 + threadIdx.x;   // grid 1792*256 = 2048*224 exact
    int b = idx / 224, d = idx % 224;
    float out = 0.f;
    if (d < 200) {
        float m = colsum[d] * (1.f / 2048.f);
        float v = fmaxf(colsumsq[d] * (1.f / 2048.f) - m * m, 0.f);
        float val = g2[d] * (h[(size_t)b * 208 + d] - m) * rsqrtf(v + EPSB) + b2[d];
        out = fmaxf(val, 0.f);
    }
    h2[idx] = f2bf(out);
}

// ---------------- K6: out = h2 @ n_feats^T + ent_bias (64 rows/block, XCD-chunk swizzle, NT stores) ----------------
__launch_bounds__(256)
__global__ void k_out(const unsigned short* __restrict__ h2, const unsigned short* __restrict__ nfb,
                      const float* __restrict__ entb, float* __restrict__ out) {
    __shared__ unsigned short At[64 * 232];     // 64 rows x 224 (stride 232 -> 2-way bank, free)
    // T1: grid 25024 = 32 mblk (fast) * 782 nblk; chunk logical tiles per XCD so the
    // 32 blocks sharing one nfb slice run on ONE XCD -> slice L2-resident (fetched once/XCD).
    int bid = blockIdx.x;                       // 25024 % 8 == 0 -> bijective
    int L = (bid & 7) * 3128 + (bid >> 3);
    int mblk = L & 31, nblk = L >> 5;
    int t = threadIdx.x, wave = t >> 6, lane = t & 63;
    int l15 = lane & 15, l4 = lane >> 4;

    const unsigned short* hbase = h2 + (size_t)mblk * 64 * 224;
    for (int f = t; f < 1792; f += 256) {       // 64 rows * 28 x 16B
        int row = f / 28, g = f % 28;
        *(uint4*)(&At[row * 232 + g * 8]) = *(const uint4*)(hbase + (size_t)row * 224 + g * 8);
    }
    __syncthreads();

    f32x4 acc[4] = {};
    int e = nblk * 64 + wave * 16 + l15;
    const unsigned short* brow = nfb + (size_t)e * 224;
    short8 bfr[7];
    #pragma unroll
    for (int ks = 0; ks < 7; ++ks)
        bfr[ks] = *(const short8*)(brow + ks * 32 + l4 * 8);
    #pragma unroll
    for (int ks = 0; ks < 7; ++ks) {
        #pragma unroll
        for (int mt = 0; mt < 4; ++mt) {
            short8 af = *(const short8*)(&At[(mt * 16 + l15) * 232 + ks * 32 + l4 * 8]);
            acc[mt] = __builtin_amdgcn_mfma_f32_16x16x32_bf16(af, bfr[ks], acc[mt], 0, 0, 0);
        }
    }
    if (e < NENT) {
        float eb = entb[e];
        #pragma unroll
        for (int mt = 0; mt < 4; ++mt) {
            #pragma unroll
            for (int r = 0; r < 4; ++r) {
                int row = mblk * 64 + mt * 16 + l4 * 4 + r;
                // out is write-once, never re-read: keep it out of L2 so nfb stays resident
                __builtin_nontemporal_store(acc[mt][r] + eb, &out[(size_t)row * NENT + e]);
            }
        }
    }
}

extern "C" void kernel_launch(void* const* d_in, const int* in_sizes, int n_in,
                              void* d_out, int out_size, void* d_ws, size_t ws_size,
                              hipStream_t stream) {
    const float* n_feats  = (const float*)d_in[0];
    const float* r_feats  = (const float*)d_in[1];
    const float* filter_w = (const float*)d_in[2];
    const float* bn0_g = (const float*)d_in[3];
    const float* bn0_b = (const float*)d_in[4];
    const float* cbn_g = (const float*)d_in[5];
    const float* cbn_b = (const float*)d_in[6];
    const float* bn1_g = (const float*)d_in[7];
    const float* bn1_b = (const float*)d_in[8];
    const float* fc_w  = (const float*)d_in[9];
    // d_in[10] = fc_b : cancels exactly through training-mode bn1d (shift-invariant)
    const float* bn2_g = (const float*)d_in[11];
    const float* bn2_b = (const float*)d_in[12];
    const float* ent_bias = (const float*)d_in[13];
    const int* sub = (const int*)d_in[14];
    const int* rel = (const int*)d_in[15];
    float* out = (float*)d_out;

    char* ws = (char*)d_ws;
    // workspace layout (all 512B-aligned)
    float*          stats = (float*)(ws + 0);                 // 8192 B region
    float*          colsum  = stats + 130;
    float*          colsumsq= stats + 338;
    float*          scaleA  = stats + 1024;
    float*          biasA   = stats + 1088;
    float*          x    = (float*)(ws + 8192);                            // 3,276,800
    unsigned short* z    = (unsigned short*)(ws + 3284992);                // 104,857,600
    unsigned short* fcwb = (unsigned short*)(ws + 108142592);              // 10,649,600
    float*          hp   = (float*)(ws + 118792192);                       // 27,262,976
    float*          h    = (float*)(ws + 146055168);                       // 1,703,936
    unsigned short* h2   = (unsigned short*)(ws + 147759104);              // 917,504
    unsigned short* nfb  = (unsigned short*)(ws + 148676608);              // 22,421,504

    // scratch partials live inside hp's region: hp is fully overwritten by k_fc,
    // which runs only after k_gfin/k_chfin have consumed these (stream-ordered).
    float*          gpart  = (float*)(ws + 118792192);                     // 12800*2*4 = 102,400
    float*          chpart = (float*)(ws + 118792192 + 131072);            // 2048*128*4 = 1,048,576

    hipMemsetAsync(stats, 0, 8192, stream);    // colsum/colsumsq zeroing (k_hred atomics)

    k_gather<<<3200, 256, 0, stream>>>(n_feats, r_feats, sub, rel, x, gpart);
    k_gfin<<<1, 256, 0, stream>>>(gpart, stats);
    k_fcw<<<2600, 256, 0, stream>>>(fc_w, fcwb);
    k_nfb<<<5474, 256, 0, stream>>>(n_feats, nfb);
    k_conv<<<2048, 256, 0, stream>>>(x, filter_w, rel, bn0_g, bn0_b, stats, z, chpart);
    k_chfin<<<64, 256, 0, stream>>>(chpart, cbn_g, cbn_b, bn1_g, bn1_b, scaleA, biasA);
    k_fc<<<512, 256, 0, stream>>>(z, fcwb, scaleA, biasA, hp);
    k_hred<<<256, 256, 0, stream>>>(hp, h, colsum, colsumsq);
    k_bnapply<<<1792, 256, 0, stream>>>(h, colsum, colsumsq, bn2_g, bn2_b, h2);
    k_out<<<25024, 256, 0, stream>>>(h2, nfb, ent_bias, out);
}